// Round 5
// baseline (374.892 us; speedup 1.0000x reference)
//
#include <hip/hip_runtime.h>

// Problem: inputs (B=32, L=720, C=862) f32. Output (T=4, B, C, L) f32 spikes.
// x is broadcast across T => element-wise 4-step LIF. Memory-bound:
// ~79.4 MB read (+straddle) + 317.8 MB write => ~63-66 us kernel roofline.
//
// R7: occupancy-discriminator. TC 16->8: LDS 46.3KB -> 23.2KB => 6 blocks/CU
// (24 waves vs 12), phases half as long. If the kernel is latency/occupancy
// bound (~163us model) this is a big win; if it is already BW-bound (~66us
// model, residual dur = harness fill+resets) this is flat and we are at the
// roofline. Keeps every proven element: XCD-chunked bijective remap (R6,
// -9us), t-major full-row nt stores (R4-best), 2-way-max LDS banks.
// Grid 108 x 32 = 3456 = 8 XCD * 432; slab = 4 b x 108 c-tiles per XCD.

#define B_DIM 32
#define L_DIM 720
#define C_DIM 862
#define T_STEPS 4
#define TC 8
#define NCT 108  // ceil(862/8)
#define SL 724   // LDS l-stride per c row (floats): %4==0 (b128), %8==4 (banks)

typedef float v2f __attribute__((ext_vector_type(2)));
typedef float v4f __attribute__((ext_vector_type(4)));

__device__ __forceinline__ void lif4(const v4f x, v4f s[T_STEPS]) {
    // LIF: v += (x - v)*0.5 ; s = (v>=1) ; v = s ? 0 : v   (exact ref arith)
    float v0 = 0.f, v1 = 0.f, v2 = 0.f, v3 = 0.f;
#pragma unroll
    for (int t = 0; t < T_STEPS; ++t) {
        v0 += (x.x - v0) * 0.5f;
        v1 += (x.y - v1) * 0.5f;
        v2 += (x.z - v2) * 0.5f;
        v3 += (x.w - v3) * 0.5f;
        v4f o;
        o.x = (v0 >= 1.0f) ? 1.0f : 0.0f;
        o.y = (v1 >= 1.0f) ? 1.0f : 0.0f;
        o.z = (v2 >= 1.0f) ? 1.0f : 0.0f;
        o.w = (v3 >= 1.0f) ? 1.0f : 0.0f;
        s[t] = o;
        v0 = (v0 >= 1.0f) ? 0.0f : v0;
        v1 = (v1 >= 1.0f) ? 0.0f : v1;
        v2 = (v2 >= 1.0f) ? 0.0f : v2;
        v3 = (v3 >= 1.0f) ? 0.0f : v3;
    }
}

__global__ __launch_bounds__(256)
void lif_repeat_encoder(const float* __restrict__ in, float* __restrict__ out) {
    __shared__ float sm[TC * SL];   // 23,168 B -> 6 blocks/CU

    // ---- XCD-chunked bijective remap (grid 108x32 = 3456 = 8 XCD * 432).
    const int wgid = blockIdx.x + (int)gridDim.x * blockIdx.y;
    const int xcd  = wgid & 7;
    const int n    = wgid >> 3;              // 0..431
    const int ct   = n % NCT;                // c-tile within slab
    const int b    = (n / NCT) + (xcd << 2); // 4 b-slabs per XCD
    const int c0   = ct * TC;
    const int tid  = threadIdx.x;

    const float* __restrict__ inb = in + (size_t)b * (L_DIM * C_DIM);

    // ---- Load phase: rows l, 2 consecutive c per lane (float2, 8B-aligned:
    // row stride 3448 B and c even keep %8==0). 4 lanes cover the 8-c tile
    // per row; 256 threads = 64 rows per round; 4 rounds batched for MLP.
    {
        const int cl2 = (tid & 3) << 1;   // c_local: 0,2,4,6
        const int c   = c0 + cl2;
        const int r0  = tid >> 2;         // 0..63
        if (c < C_DIM) {                  // tail tile (c0=856) has 6 cols: cl2=6 inactive
            for (int base = 0; base < L_DIM; base += 256) {
                v2f v[4];
#pragma unroll
                for (int u = 0; u < 4; ++u) {
                    const int r = base + r0 + 64 * u;
                    if (r < L_DIM)
                        v[u] = *(const v2f*)(inb + (size_t)r * C_DIM + c);
                }
#pragma unroll
                for (int u = 0; u < 4; ++u) {
                    const int r = base + r0 + 64 * u;
                    if (r < L_DIM) {
                        sm[cl2 * SL + r]       = v[u].x;
                        sm[(cl2 + 1) * SL + r] = v[u].y;
                    }
                }
            }
        }
    }
    __syncthreads();

    // ---- Store phase: wave w handles c_local = 2w, 2w+1. Per (c,t) the wave
    // writes the FULL 720-float row (3 float4 bursts: 64+64+52 lanes)
    // back-to-back before switching t-plane.
    const int wave = tid >> 6;   // 0..3
    const int lane = tid & 63;
    const size_t plane = (size_t)B_DIM * C_DIM * L_DIM;

#pragma unroll
    for (int q = 0; q < 2; ++q) {
        const int cl = wave * 2 + q;
        const int c  = c0 + cl;
        if (c >= C_DIM) continue;

        const size_t rowbase = ((size_t)b * C_DIM + c) * L_DIM;
        const float* sr = sm + cl * SL;

        const int j0 = lane;              // < 180 always
        const int j1 = lane + 64;         // < 180 always (<=127)
        const int j2 = lane + 128;        // valid iff lane < 52
        const int j2c = (j2 < L_DIM / 4) ? j2 : (L_DIM / 4 - 1);  // clamp: keep LDS read in-bounds

        const v4f x0 = *(const v4f*)(sr + 4 * j0);
        const v4f x1 = *(const v4f*)(sr + 4 * j1);
        const v4f x2 = *(const v4f*)(sr + 4 * j2c);

        v4f s0[T_STEPS], s1[T_STEPS], s2[T_STEPS];
        lif4(x0, s0);
        lif4(x1, s1);
        lif4(x2, s2);

#pragma unroll
        for (int t = 0; t < T_STEPS; ++t) {
            float* op = out + (size_t)t * plane + rowbase;
            __builtin_nontemporal_store(s0[t], (v4f*)(op + 4 * j0));
            __builtin_nontemporal_store(s1[t], (v4f*)(op + 4 * j1));
            if (j2 < L_DIM / 4)
                __builtin_nontemporal_store(s2[t], (v4f*)(op + 4 * j2));
        }
    }
}

extern "C" void kernel_launch(void* const* d_in, const int* in_sizes, int n_in,
                              void* d_out, int out_size, void* d_ws, size_t ws_size,
                              hipStream_t stream) {
    const float* in = (const float*)d_in[0];
    float* out = (float*)d_out;

    dim3 block(256, 1, 1);
    dim3 grid(NCT,     // 108
              B_DIM,   // 32
              1);

    lif_repeat_encoder<<<grid, block, 0, stream>>>(in, out);
}

// Round 6
// 371.899 us; speedup vs baseline: 1.0080x; 1.0080x over previous
//
#include <hip/hip_runtime.h>

// Problem: inputs (B=32, L=720, C=862) f32. Output (T=4, B, C, L) f32 spikes.
// x is broadcast across T => element-wise 4-step LIF. Memory-bound:
// ~79.4 MB read (+straddle) + 317.8 MB write => ~61-63 us kernel roofline.
//
// R8 = R6 revert (best measured: 356.9 us). R7 (TC=8, 2x occupancy) was
// +13 us fill-normalized => latency/occupancy model falsified; kernel is
// BW-bound at ~66 us, residual dur is harness fill (~194 us) + reset train.
// Proven elements kept:
//  - XCD-chunked bijective remap (R6, -9 us): input row stride 3448 B ==
//    56 mod 64 -> every 64 B tile-row segment straddles 2 lines; remap puts
//    straddle partners (c-adjacent tiles) on the same XCD L2 and walks all
//    54 c-tiles of a b-slab consecutively -> slab read ~once per XCD.
//  - t-major full-row stores (R4): per (c,t) the full 2880 B row is written
//    back-to-back; three structurally different store orders measured
//    identical, store path is not the bottleneck.
//  - nontemporal stores (measured best twice; plain stores neutral w/ noise).
//  - TC=16 (measured better than TC=8 twice): 64 B useful per straddled
//    line-pair, LDS 46.3 KB -> 3 blocks/CU suffices (BW-bound, not latency).

#define B_DIM 32
#define L_DIM 720
#define C_DIM 862
#define T_STEPS 4
#define TC 16
#define SL 724   // LDS l-stride per c row (floats): %4==0 (b128), %8==4 (banks)

typedef float v2f __attribute__((ext_vector_type(2)));
typedef float v4f __attribute__((ext_vector_type(4)));

__device__ __forceinline__ void lif4(const v4f x, v4f s[T_STEPS]) {
    // LIF: v += (x - v)*0.5 ; s = (v>=1) ; v = s ? 0 : v   (exact ref arith)
    float v0 = 0.f, v1 = 0.f, v2 = 0.f, v3 = 0.f;
#pragma unroll
    for (int t = 0; t < T_STEPS; ++t) {
        v0 += (x.x - v0) * 0.5f;
        v1 += (x.y - v1) * 0.5f;
        v2 += (x.z - v2) * 0.5f;
        v3 += (x.w - v3) * 0.5f;
        v4f o;
        o.x = (v0 >= 1.0f) ? 1.0f : 0.0f;
        o.y = (v1 >= 1.0f) ? 1.0f : 0.0f;
        o.z = (v2 >= 1.0f) ? 1.0f : 0.0f;
        o.w = (v3 >= 1.0f) ? 1.0f : 0.0f;
        s[t] = o;
        v0 = (v0 >= 1.0f) ? 0.0f : v0;
        v1 = (v1 >= 1.0f) ? 0.0f : v1;
        v2 = (v2 >= 1.0f) ? 0.0f : v2;
        v3 = (v3 >= 1.0f) ? 0.0f : v3;
    }
}

__global__ __launch_bounds__(256)
void lif_repeat_encoder(const float* __restrict__ in, float* __restrict__ out) {
    __shared__ float sm[TC * SL];   // 46,336 B

    // ---- XCD-chunked bijective remap (grid 54x32 = 1728 = 8 XCD * 216).
    // HW round-robins linear wgid over XCDs: xcd = wgid % 8.
    // Within an XCD, consecutive n walk all 54 c-tiles of one b-slab first.
    const int wgid = blockIdx.x + (int)gridDim.x * blockIdx.y;
    const int xcd  = wgid & 7;
    const int n    = wgid >> 3;          // 0..215
    const int ct   = n % 54;             // c-tile within slab
    const int b    = (n / 54) + (xcd << 2);  // 4 b-slabs per XCD
    const int c0   = ct * TC;
    const int tid  = threadIdx.x;

    const float* __restrict__ inb = in + (size_t)b * (L_DIM * C_DIM);

    // ---- Load phase: rows l, 2 consecutive c per lane (float2, 8B-aligned:
    // row stride 3448 B and c even keep %8==0). 8 lanes cover the 16-c tile
    // per row; 256 threads = 32 rows per round; 4 rounds batched for MLP.
    {
        const int cl2 = (tid & 7) << 1;   // c_local: 0,2,...,14
        const int c   = c0 + cl2;
        const int r0  = tid >> 3;         // 0..31
        if (c < C_DIM) {                  // tail tile (c0=848) has 14 cols: cl2=14 inactive
            for (int base = 0; base < L_DIM; base += 128) {
                v2f v[4];
#pragma unroll
                for (int u = 0; u < 4; ++u) {
                    const int r = base + r0 + 32 * u;
                    if (r < L_DIM)
                        v[u] = *(const v2f*)(inb + (size_t)r * C_DIM + c);
                }
#pragma unroll
                for (int u = 0; u < 4; ++u) {
                    const int r = base + r0 + 32 * u;
                    if (r < L_DIM) {
                        sm[cl2 * SL + r]       = v[u].x;
                        sm[(cl2 + 1) * SL + r] = v[u].y;
                    }
                }
            }
        }
    }
    __syncthreads();

    // ---- Store phase: wave w handles c_local = 4w..4w+3. Per (c,t) the wave
    // writes the FULL 720-float row (3 float4 bursts: 64+64+52 lanes)
    // back-to-back before switching t-plane.
    const int wave = tid >> 6;   // 0..3
    const int lane = tid & 63;
    const size_t plane = (size_t)B_DIM * C_DIM * L_DIM;

#pragma unroll
    for (int q = 0; q < 4; ++q) {
        const int cl = wave * 4 + q;
        const int c  = c0 + cl;
        if (c >= C_DIM) continue;

        const size_t rowbase = ((size_t)b * C_DIM + c) * L_DIM;
        const float* sr = sm + cl * SL;

        const int j0 = lane;              // < 180 always
        const int j1 = lane + 64;         // < 180 always (<=127)
        const int j2 = lane + 128;        // valid iff lane < 52
        const int j2c = (j2 < L_DIM / 4) ? j2 : (L_DIM / 4 - 1);  // clamp: keep LDS read in-bounds

        const v4f x0 = *(const v4f*)(sr + 4 * j0);
        const v4f x1 = *(const v4f*)(sr + 4 * j1);
        const v4f x2 = *(const v4f*)(sr + 4 * j2c);

        v4f s0[T_STEPS], s1[T_STEPS], s2[T_STEPS];
        lif4(x0, s0);
        lif4(x1, s1);
        lif4(x2, s2);

#pragma unroll
        for (int t = 0; t < T_STEPS; ++t) {
            float* op = out + (size_t)t * plane + rowbase;
            __builtin_nontemporal_store(s0[t], (v4f*)(op + 4 * j0));
            __builtin_nontemporal_store(s1[t], (v4f*)(op + 4 * j1));
            if (j2 < L_DIM / 4)
                __builtin_nontemporal_store(s2[t], (v4f*)(op + 4 * j2));
        }
    }
}

extern "C" void kernel_launch(void* const* d_in, const int* in_sizes, int n_in,
                              void* d_out, int out_size, void* d_ws, size_t ws_size,
                              hipStream_t stream) {
    const float* in = (const float*)d_in[0];
    float* out = (float*)d_out;

    dim3 block(256, 1, 1);
    dim3 grid((C_DIM + TC - 1) / TC,   // 54
              B_DIM,                   // 32
              1);

    lif_repeat_encoder<<<grid, block, 0, stream>>>(in, out);
}